// Round 6
// baseline (227.955 us; speedup 1.0000x reference)
//
#include <hip/hip_runtime.h>

// T5-style MHA: B=2, S=2048, H=16, Dkv=64, Dmodel=1024. f32 in/out, bf16 MFMA inside.
// R6: kv-split attention — 8 waves/block, waves 0-3 kv[0,1024), waves 4-7 kv[1024,2048),
//     partials combine by addition (no-max softmax => linear), LDS combine in epilogue.
//     2x waves/SIMD (2->4). exp2 via builtin. bias LUT merged into transpose kernel.

typedef __attribute__((ext_vector_type(8))) short s16x8;
typedef __attribute__((ext_vector_type(4))) float f32x4;
typedef __attribute__((ext_vector_type(16))) float f32x16;
typedef __attribute__((ext_vector_type(2))) unsigned int u32x2;

#if __has_builtin(__builtin_amdgcn_exp2f)
#define EXP2(x) __builtin_amdgcn_exp2f(x)
#else
#define EXP2(x) exp2f(x)
#endif

__device__ __forceinline__ unsigned short f2bf(float f) {
  unsigned int u = __float_as_uint(f);
  u = (u + 0x7fffu + ((u >> 16) & 1u)) >> 16;  // RNE
  return (unsigned short)u;
}

__device__ __forceinline__ unsigned cvtpk(float lo, float hi) {
  unsigned r;
  asm("v_cvt_pk_bf16_f32 %0, %1, %2" : "=v"(r) : "v"(lo), "v"(hi));
  return r;
}

#define GLD16(g, l)                                              \
  __builtin_amdgcn_global_load_lds(                              \
      (const __attribute__((address_space(1))) void*)(g),        \
      (__attribute__((address_space(3))) void*)(l), 16, 0, 0)

// ---------------- convert f32 -> bf16, linear ----------------
__global__ __launch_bounds__(256) void cvt_lin(const float* __restrict__ in,
                                               unsigned short* __restrict__ out,
                                               int n4) {
  int i = blockIdx.x * 256 + threadIdx.x;
  int stride = gridDim.x * 256;
  for (; i < n4; i += stride) {
    float4 v = ((const float4*)in)[i];
    ushort4 o;
    o.x = f2bf(v.x); o.y = f2bf(v.y); o.z = f2bf(v.z); o.w = f2bf(v.w);
    ((ushort4*)out)[i] = o;
  }
}

// ---------------- prep: z<4 -> W transpose+cvt; z==4 -> bias LUT (pre-scaled log2 e) ----------------
__global__ __launch_bounds__(256) void cvt_prep(const float* __restrict__ W0,
                                                const float* __restrict__ W1,
                                                const float* __restrict__ W2,
                                                const float* __restrict__ W3,
                                                const float* __restrict__ rel,
                                                unsigned short* __restrict__ Dqkv,
                                                unsigned short* __restrict__ Do_,
                                                float* __restrict__ tab) {
  const int z = blockIdx.z;
  if (z == 4) {
    int idx = (blockIdx.y * 32 + blockIdx.x) * 256 + threadIdx.x;
    if (idx >= 16 * 4096) return;
    int h = idx >> 12, di = idx & 4095;
    int delta = di - 2047;  // k - q
    int n = -delta;         // q - k
    int ret = (n < 0) ? 16 : 0;
    n = n < 0 ? -n : n;
    int bucket;
    if (n < 8) {
      bucket = ret + n;
    } else {
      float lf = (float)log((double)n * 0.125);  // correctly-rounded f32 log
      float f = lf / 2.772588722239781f * 8.0f;
      int v = 8 + (int)f;
      bucket = ret + (v < 15 ? v : 15);
    }
    tab[idx] = rel[bucket * 16 + h] * 1.4426950408889634f;
    return;
  }
  const float* W = (z == 0) ? W0 : (z == 1) ? W1 : (z == 2) ? W2 : W3;
  unsigned short* WT = (z < 3) ? (Dqkv + (size_t)z * 1024 * 1024) : Do_;
  __shared__ float t[32][33];
  int n0 = blockIdx.x * 32, k0 = blockIdx.y * 32;
  int tx = threadIdx.x & 31, ty = threadIdx.x >> 5;
#pragma unroll
  for (int i = 0; i < 32; i += 8)
    t[ty + i][tx] = W[(size_t)(k0 + ty + i) * 1024 + n0 + tx];
  __syncthreads();
#pragma unroll
  for (int i = 0; i < 32; i += 8)
    WT[(size_t)(n0 + ty + i) * 1024 + k0 + tx] = f2bf(t[tx][ty + i]);
}

// ---------------- 128x128 tile GEMM, fused QKV; Q output pre-scaled by log2(e) ----------------
__global__ __launch_bounds__(256, 2) void gemm_qkv(
    const unsigned short* __restrict__ A, const unsigned short* __restrict__ BT,
    unsigned short* __restrict__ O0, unsigned short* __restrict__ O1,
    unsigned short* __restrict__ O2) {
  __shared__ __align__(16) unsigned short aT[128 * 64];
  __shared__ __align__(16) unsigned short bT[128 * 64];
  const int tid = threadIdx.x;
  const int lane = tid & 63, w = tid >> 6;
  const int l15 = lane & 15, l4 = lane >> 4;
  const int m0 = blockIdx.y * 128, n0 = blockIdx.x * 128;
  const int wr = w >> 1, wc = w & 1;

  const f32x4 fzero = {0.f, 0.f, 0.f, 0.f};
  f32x4 acc[4][4];
#pragma unroll
  for (int i = 0; i < 4; ++i)
#pragma unroll
    for (int j = 0; j < 4; ++j) acc[i][j] = fzero;

  for (int k0 = 0; k0 < 1024; k0 += 64) {
#pragma unroll
    for (int p = 0; p < 4; ++p) {
      int slot = (p * 4 + w) * 64 + lane;
      int row = slot >> 3, s = slot & 7;
      int ks = (s ^ (row & 7)) << 3;  // XOR swizzle on 16B slots
      GLD16(A + (size_t)(m0 + row) * 1024 + k0 + ks, (char*)aT + (p * 4 + w) * 1024);
      GLD16(BT + (size_t)(n0 + row) * 1024 + k0 + ks, (char*)bT + (p * 4 + w) * 1024);
    }
    __syncthreads();
#pragma unroll
    for (int kk = 0; kk < 2; ++kk) {
      int slotk = kk * 4 + l4;
      s16x8 af[4], bfr[4];
#pragma unroll
      for (int mi = 0; mi < 4; ++mi) {
        int row = wr * 64 + mi * 16 + l15;
        af[mi] = *(const s16x8*)(aT + row * 64 + ((slotk ^ (row & 7)) << 3));
      }
#pragma unroll
      for (int nj = 0; nj < 4; ++nj) {
        int row = wc * 64 + nj * 16 + l15;
        bfr[nj] = *(const s16x8*)(bT + row * 64 + ((slotk ^ (row & 7)) << 3));
      }
      __builtin_amdgcn_s_setprio(1);
#pragma unroll
      for (int mi = 0; mi < 4; ++mi)
#pragma unroll
        for (int nj = 0; nj < 4; ++nj)
          acc[mi][nj] = __builtin_amdgcn_mfma_f32_16x16x32_bf16(af[mi], bfr[nj], acc[mi][nj], 0, 0, 0);
      __builtin_amdgcn_s_setprio(0);
    }
    __syncthreads();
  }

#pragma unroll
  for (int mi = 0; mi < 4; ++mi)
#pragma unroll
    for (int nj = 0; nj < 4; ++nj)
#pragma unroll
      for (int r = 0; r < 4; ++r) {
        int row = m0 + wr * 64 + mi * 16 + l4 * 4 + r;  // C/D: col=lane&15, row=(lane>>4)*4+r
        int col = n0 + wc * 64 + nj * 16 + l15;
        int which = col >> 10;
        int cc = col & 1023;
        int b = row >> 11, s2 = row & 2047, hh = cc >> 6, d = cc & 63;
        if (which == 0)  // Q: pre-scale by log2(e) so attn exp2 arg is the raw accumulator
          O0[((size_t)((b * 16 + hh) * 2048 + s2)) * 64 + d] =
              f2bf(acc[mi][nj][r] * 1.4426950408889634f);
        else if (which == 1)
          O1[((size_t)((b * 16 + hh) * 2048 + s2)) * 64 + d] = f2bf(acc[mi][nj][r]);
        else
          O2[((size_t)((b * 16 + hh) * 64 + d)) * 2048 + s2] = f2bf(acc[mi][nj][r]);
      }
}

// ---------------- out-proj GEMM: 128x64 tiles, out f32 [4096][1024] ----------------
__global__ __launch_bounds__(256, 2) void gemm_op(
    const unsigned short* __restrict__ A, const unsigned short* __restrict__ BT,
    float* __restrict__ O) {
  __shared__ __align__(16) unsigned short aT[128 * 64];
  __shared__ __align__(16) unsigned short bT[64 * 64];
  const int tid = threadIdx.x;
  const int lane = tid & 63, w = tid >> 6;
  const int l15 = lane & 15, l4 = lane >> 4;
  const int m0 = blockIdx.y * 128, n0 = blockIdx.x * 64;
  const int wr = w >> 1, wc = w & 1;

  const f32x4 fzero = {0.f, 0.f, 0.f, 0.f};
  f32x4 acc[4][2];
#pragma unroll
  for (int i = 0; i < 4; ++i)
#pragma unroll
    for (int j = 0; j < 2; ++j) acc[i][j] = fzero;

  for (int k0 = 0; k0 < 1024; k0 += 64) {
#pragma unroll
    for (int p = 0; p < 4; ++p) {
      int slot = (p * 4 + w) * 64 + lane;
      int row = slot >> 3, s = slot & 7;
      int ks = (s ^ (row & 7)) << 3;
      GLD16(A + (size_t)(m0 + row) * 1024 + k0 + ks, (char*)aT + (p * 4 + w) * 1024);
    }
#pragma unroll
    for (int p = 0; p < 2; ++p) {
      int slot = (p * 4 + w) * 64 + lane;
      int row = slot >> 3, s = slot & 7;
      int ks = (s ^ (row & 7)) << 3;
      GLD16(BT + (size_t)(n0 + row) * 1024 + k0 + ks, (char*)bT + (p * 4 + w) * 1024);
    }
    __syncthreads();
#pragma unroll
    for (int kk = 0; kk < 2; ++kk) {
      int slotk = kk * 4 + l4;
      s16x8 af[4], bfr[2];
#pragma unroll
      for (int mi = 0; mi < 4; ++mi) {
        int row = wr * 64 + mi * 16 + l15;
        af[mi] = *(const s16x8*)(aT + row * 64 + ((slotk ^ (row & 7)) << 3));
      }
#pragma unroll
      for (int nj = 0; nj < 2; ++nj) {
        int row = wc * 32 + nj * 16 + l15;
        bfr[nj] = *(const s16x8*)(bT + row * 64 + ((slotk ^ (row & 7)) << 3));
      }
      __builtin_amdgcn_s_setprio(1);
#pragma unroll
      for (int mi = 0; mi < 4; ++mi)
#pragma unroll
        for (int nj = 0; nj < 2; ++nj)
          acc[mi][nj] = __builtin_amdgcn_mfma_f32_16x16x32_bf16(af[mi], bfr[nj], acc[mi][nj], 0, 0, 0);
      __builtin_amdgcn_s_setprio(0);
    }
    __syncthreads();
  }

#pragma unroll
  for (int mi = 0; mi < 4; ++mi)
#pragma unroll
    for (int nj = 0; nj < 2; ++nj)
#pragma unroll
      for (int r = 0; r < 4; ++r) {
        int row = m0 + wr * 64 + mi * 16 + l4 * 4 + r;
        int col = n0 + wc * 32 + nj * 16 + l15;
        O[(size_t)row * 1024 + col] = acc[mi][nj][r];
      }
}

// ---------------- flash attention, kv-split, swapped 32x32 MFMA, NO-MAX softmax ----------------
// grid (16, 32), 512 threads. 128 q-rows/block; wave w: q sub-tile (w&3), kv half (w>>2).
// Each kv half: 16 tiles of 64, double-buffered. Partials combined by addition in LDS.
__global__ __launch_bounds__(512, 4) void attn_k(
    const unsigned short* __restrict__ Q,   // [32][2048][64], pre-scaled by log2(e)
    const unsigned short* __restrict__ K,   // [32][2048][64]
    const unsigned short* __restrict__ VT,  // [32][64][2048]
    const float* __restrict__ btab,         // [16][4096], pre-scaled by log2(e)
    unsigned short* __restrict__ H) {       // [2][2048][1024] bf16
  // layout: stream st (0/1): K at st*32768 + buf*8192, V at st*32768 + 16384 + buf*8192
  __shared__ __align__(16) char smem[65536];
  const int tid = threadIdx.x;
  const int lane = tid & 63, w = tid >> 6;
  const int l31 = lane & 31, l5 = lane >> 5;
  const int half = w >> 2;                 // kv stream
  const int q0 = blockIdx.x * 128 + (w & 3) * 32;
  const int bh = blockIdx.y, h = bh & 15, b = bh >> 4;
  const unsigned short* Qp = Q + (size_t)bh * 2048 * 64;
  const unsigned short* Kp = K + (size_t)bh * 2048 * 64;
  const unsigned short* Vp = VT + (size_t)bh * 64 * 2048;
  const float* btq = btab + h * 4096 + 2047 - (q0 + l31) + 4 * l5 + half * 1024;

// stage K+V for BOTH streams, tile kvv (relative to stream base), into buffer `buf`
#define STAGE(buf, kvv)                                                              \
  {                                                                                  \
    int row_ = tid >> 3, s_ = tid & 7;                                               \
    int ks_ = (s_ ^ (row_ & 7)) << 3;                                                \
    GLD16(Kp + (size_t)((kvv) + row_) * 64 + ks_, smem + (buf) * 8192 + tid * 16);   \
    GLD16(Kp + (size_t)(1024 + (kvv) + row_) * 64 + ks_,                             \
          smem + 32768 + (buf) * 8192 + tid * 16);                                   \
    GLD16(Vp + (size_t)row_ * 2048 + (kvv) + ks_,                                    \
          smem + 16384 + (buf) * 8192 + tid * 16);                                   \
    GLD16(Vp + (size_t)row_ * 2048 + 1024 + (kvv) + ks_,                             \
          smem + 16384 + 32768 + (buf) * 8192 + tid * 16);                           \
  }

#define LOADB(dst, kvv)                                                              \
  {                                                                                  \
    _Pragma("unroll") for (int t_ = 0; t_ < 2; ++t_)                                 \
      _Pragma("unroll") for (int r_ = 0; r_ < 16; ++r_)                              \
        dst[t_ * 16 + r_] = btq[(kvv) + t_ * 32 + (r_ & 3) + 8 * (r_ >> 2)];         \
  }

  // hoist Q fragments (B operand: col=q=l31, k = ks*16 + l5*8 + j)
  s16x8 qf[4];
#pragma unroll
  for (int ks = 0; ks < 4; ++ks)
    qf[ks] = *(const s16x8*)(Qp + (size_t)(q0 + l31) * 64 + ks * 16 + l5 * 8);

  f32x16 oacc[2];
#pragma unroll
  for (int r = 0; r < 16; ++r) { oacc[0][r] = 0.f; oacc[1][r] = 0.f; }
  float s4[4] = {0.f, 0.f, 0.f, 0.f};  // lane-local running row-sum partials

  float ba[32], bb[32];  // bias ping-pong (compile-time indices -> registers)
  LOADB(ba, 0);
  STAGE(0, 0);
  __syncthreads();
  int cur = 0;
  const char* kbase = smem + half * 32768;
  const char* vbase = smem + half * 32768 + 16384;

#define BODY(KVV, BC, BN_)                                                           \
  {                                                                                  \
    const int kvv = (KVV);                                                           \
    if (kvv + 64 < 1024) STAGE(cur ^ 1, kvv + 64);                                   \
    f32x16 st[2];                                                                    \
    _Pragma("unroll") for (int t = 0; t < 2; ++t)                                    \
      _Pragma("unroll") for (int r = 0; r < 16; ++r)                                 \
        st[t][r] = BC[t * 16 + r];                                                   \
    if (kvv + 64 < 1024) LOADB(BN_, kvv + 64);                                       \
    const char* kl = kbase + cur * 8192;                                             \
    __builtin_amdgcn_s_setprio(1);                                                   \
    _Pragma("unroll") for (int ks = 0; ks < 4; ++ks) {                               \
      int sl = ks * 2 + l5;                                                          \
      int sw = (sl ^ (l31 & 7)) << 4;                                                \
      s16x8 ka0 = *(const s16x8*)(kl + l31 * 128 + sw);                              \
      s16x8 ka1 = *(const s16x8*)(kl + (32 + l31) * 128 + sw);                       \
      st[0] = __builtin_amdgcn_mfma_f32_32x32x16_bf16(ka0, qf[ks], st[0], 0, 0, 0);  \
      st[1] = __builtin_amdgcn_mfma_f32_32x32x16_bf16(ka1, qf[ks], st[1], 0, 0, 0);  \
    }                                                                                \
    __builtin_amdgcn_s_setprio(0);                                                   \
    _Pragma("unroll") for (int t = 0; t < 2; ++t)                                    \
      _Pragma("unroll") for (int r = 0; r < 16; ++r) {                               \
        float p_ = EXP2(st[t][r]);                                                   \
        st[t][r] = p_;                                                               \
        s4[r & 3] += p_;                                                             \
      }                                                                              \
    s16x8 pb[4];                                                                     \
    _Pragma("unroll") for (int t = 0; t < 2; ++t)                                    \
      _Pragma("unroll") for (int hh = 0; hh < 2; ++hh) {                             \
        unsigned cA = cvtpk(st[t][hh * 8 + 0], st[t][hh * 8 + 1]);                   \
        unsigned cB = cvtpk(st[t][hh * 8 + 2], st[t][hh * 8 + 3]);                   \
        unsigned cC = cvtpk(st[t][hh * 8 + 4], st[t][hh * 8 + 5]);                   \
        unsigned cD = cvtpk(st[t][hh * 8 + 6], st[t][hh * 8 + 7]);                   \
        u32x2 s1 = __builtin_amdgcn_permlane32_swap(cA, cC, false, false);           \
        u32x2 s2 = __builtin_amdgcn_permlane32_swap(cB, cD, false, false);           \
        union { unsigned u[4]; s16x8 v; } pu;                                        \
        pu.u[0] = s1.x; pu.u[1] = s2.x; pu.u[2] = s1.y; pu.u[3] = s2.y;              \
        pb[t * 2 + hh] = pu.v;                                                       \
      }                                                                              \
    const char* vl = vbase + cur * 8192;                                             \
    __builtin_amdgcn_s_setprio(1);                                                   \
    _Pragma("unroll") for (int ks2 = 0; ks2 < 4; ++ks2) {                            \
      int sl = ks2 * 2 + l5;                                                         \
      int sw = (sl ^ (l31 & 7)) << 4;                                                \
      s16x8 va0 = *(const s16x8*)(vl + l31 * 128 + sw);                              \
      s16x8 va1 = *(const s16x8*)(vl + (32 + l31) * 128 + sw);                       \
      oacc[0] = __builtin_amdgcn_mfma_f32_32x32x16_bf16(va0, pb[ks2], oacc[0], 0, 0, 0); \
      oacc[1] = __builtin_amdgcn_mfma_f32_32x32x16_bf16(va1, pb[ks2], oacc[1], 0, 0, 0); \
    }                                                                                \
    __builtin_amdgcn_s_setprio(0);                                                   \
    __syncthreads();                                                                 \
    cur ^= 1;                                                                        \
  }

  for (int s = 0; s < 8; ++s) {
    BODY(s * 128, ba, bb);
    BODY(s * 128 + 64, bb, ba);
  }
#undef BODY
#undef LOADB
#undef STAGE

  // per-wave row sum: lane partials + cross-half swap (both halves share q=l31)
  float sum = (s4[0] + s4[1]) + (s4[2] + s4[3]);
  u32x2 rs = __builtin_amdgcn_permlane32_swap(__float_as_uint(sum), __float_as_uint(sum), false, false);
  float lsum = __uint_as_float(rs.x) + __uint_as_float(rs.y);

  // combine kv halves: waves 4-7 publish (32 f32 O^T + sum), waves 0-3 reduce + store.
  float* comb = (float*)smem;  // 4*64*34*4B = 34816B, reuses K/V region (loop done)
  if (w >= 4) {
    float* p = comb + ((w - 4) * 64 + lane) * 34;
#pragma unroll
    for (int r = 0; r < 16; ++r) { p[r] = oacc[0][r]; p[16 + r] = oacc[1][r]; }
    p[32] = lsum;
  }
  __syncthreads();
  if (w < 4) {
    const float* p = comb + (w * 64 + lane) * 34;
#pragma unroll
    for (int r = 0; r < 16; ++r) { oacc[0][r] += p[r]; oacc[1][r] += p[16 + r]; }
    float inv = 1.0f / (lsum + p[32]);
    size_t hb = (((size_t)(b * 2048 + q0 + l31)) * 1024 + h * 64 + 4 * l5) * 2;
#pragma unroll
    for (int nd = 0; nd < 2; ++nd)
#pragma unroll
      for (int g = 0; g < 4; ++g) {
        unsigned w0 = cvtpk(oacc[nd][g * 4 + 0] * inv, oacc[nd][g * 4 + 1] * inv);
        unsigned w1 = cvtpk(oacc[nd][g * 4 + 2] * inv, oacc[nd][g * 4 + 3] * inv);
        unsigned long long pk8 = (unsigned long long)w0 | ((unsigned long long)w1 << 32);
        *(unsigned long long*)((char*)H + hb + (nd * 32 + 8 * g) * 2) = pk8;
      }
  }
}

extern "C" void kernel_launch(void* const* d_in, const int* in_sizes, int n_in,
                              void* d_out, int out_size, void* d_ws, size_t ws_size,
                              hipStream_t stream) {
  const float* X   = (const float*)d_in[0];
  const float* Wq  = (const float*)d_in[1];
  const float* Wk  = (const float*)d_in[2];
  const float* Wv  = (const float*)d_in[3];
  const float* Wo  = (const float*)d_in[4];
  const float* rel = (const float*)d_in[5];

  char* ws = (char*)d_ws;
  unsigned short* Xb     = (unsigned short*)(ws);                // 8 MiB [4096][1024]
  unsigned short* Hid    = Xb;                                   // aliased after QKV gemm
  unsigned short* WqkvT  = (unsigned short*)(ws + (8u << 20));   // 6 MiB [3072][1024]
  unsigned short* WoT    = (unsigned short*)(ws + (14u << 20));  // 2 MiB
  unsigned short* Qb     = (unsigned short*)(ws + (16u << 20));  // 8 MiB [b][h][s][d]
  unsigned short* Kb     = (unsigned short*)(ws + (24u << 20));  // 8 MiB
  unsigned short* VTb    = (unsigned short*)(ws + (32u << 20));  // 8 MiB [b][h][d][s]
  float* btab            = (float*)(ws + (40u << 20));           // 256 KiB [16][4096]

  cvt_lin<<<1024, 256, 0, stream>>>(X, Xb, (2 * 2048 * 1024) / 4);
  cvt_prep<<<dim3(32, 32, 5), 256, 0, stream>>>(Wq, Wk, Wv, Wo, rel, WqkvT, WoT, btab);

  gemm_qkv<<<dim3(24, 32), 256, 0, stream>>>(Xb, WqkvT, Qb, Kb, VTb);

  attn_k<<<dim3(16, 32), 512, 0, stream>>>(Qb, Kb, VTb, btab, Hid);

  gemm_op<<<dim3(16, 32), 256, 0, stream>>>(Hid, WoT, (float*)d_out);
}

// Round 7
// 117.697 us; speedup vs baseline: 1.9368x; 1.9368x over previous
//
#include <hip/hip_runtime.h>

// T5-style MHA: B=2, S=2048, H=16, Dkv=64, Dmodel=1024. f32 in/out, bf16 MFMA inside.
// R7: R6 kv-split attention with the register economics fixed — no bias ping-pong
//     (bias loads straight into the MFMA C-in regs), __launch_bounds__(512,2) so the
//     compiler is NOT forced to spill. Target: 2 blocks/CU (needs VGPR <= 128).

typedef __attribute__((ext_vector_type(8))) short s16x8;
typedef __attribute__((ext_vector_type(4))) float f32x4;
typedef __attribute__((ext_vector_type(16))) float f32x16;
typedef __attribute__((ext_vector_type(2))) unsigned int u32x2;

#if __has_builtin(__builtin_amdgcn_exp2f)
#define EXP2(x) __builtin_amdgcn_exp2f(x)
#else
#define EXP2(x) exp2f(x)
#endif

__device__ __forceinline__ unsigned short f2bf(float f) {
  unsigned int u = __float_as_uint(f);
  u = (u + 0x7fffu + ((u >> 16) & 1u)) >> 16;  // RNE
  return (unsigned short)u;
}

__device__ __forceinline__ unsigned cvtpk(float lo, float hi) {
  unsigned r;
  asm("v_cvt_pk_bf16_f32 %0, %1, %2" : "=v"(r) : "v"(lo), "v"(hi));
  return r;
}

#define GLD16(g, l)                                              \
  __builtin_amdgcn_global_load_lds(                              \
      (const __attribute__((address_space(1))) void*)(g),        \
      (__attribute__((address_space(3))) void*)(l), 16, 0, 0)

// ---------------- convert f32 -> bf16, linear ----------------
__global__ __launch_bounds__(256) void cvt_lin(const float* __restrict__ in,
                                               unsigned short* __restrict__ out,
                                               int n4) {
  int i = blockIdx.x * 256 + threadIdx.x;
  int stride = gridDim.x * 256;
  for (; i < n4; i += stride) {
    float4 v = ((const float4*)in)[i];
    ushort4 o;
    o.x = f2bf(v.x); o.y = f2bf(v.y); o.z = f2bf(v.z); o.w = f2bf(v.w);
    ((ushort4*)out)[i] = o;
  }
}

// ---------------- prep: z<4 -> W transpose+cvt; z==4 -> bias LUT (pre-scaled log2 e) ----------------
__global__ __launch_bounds__(256) void cvt_prep(const float* __restrict__ W0,
                                                const float* __restrict__ W1,
                                                const float* __restrict__ W2,
                                                const float* __restrict__ W3,
                                                const float* __restrict__ rel,
                                                unsigned short* __restrict__ Dqkv,
                                                unsigned short* __restrict__ Do_,
                                                float* __restrict__ tab) {
  const int z = blockIdx.z;
  if (z == 4) {
    int idx = (blockIdx.y * 32 + blockIdx.x) * 256 + threadIdx.x;
    if (idx >= 16 * 4096) return;
    int h = idx >> 12, di = idx & 4095;
    int delta = di - 2047;  // k - q
    int n = -delta;         // q - k
    int ret = (n < 0) ? 16 : 0;
    n = n < 0 ? -n : n;
    int bucket;
    if (n < 8) {
      bucket = ret + n;
    } else {
      float lf = (float)log((double)n * 0.125);  // correctly-rounded f32 log
      float f = lf / 2.772588722239781f * 8.0f;
      int v = 8 + (int)f;
      bucket = ret + (v < 15 ? v : 15);
    }
    tab[idx] = rel[bucket * 16 + h] * 1.4426950408889634f;
    return;
  }
  const float* W = (z == 0) ? W0 : (z == 1) ? W1 : (z == 2) ? W2 : W3;
  unsigned short* WT = (z < 3) ? (Dqkv + (size_t)z * 1024 * 1024) : Do_;
  __shared__ float t[32][33];
  int n0 = blockIdx.x * 32, k0 = blockIdx.y * 32;
  int tx = threadIdx.x & 31, ty = threadIdx.x >> 5;
#pragma unroll
  for (int i = 0; i < 32; i += 8)
    t[ty + i][tx] = W[(size_t)(k0 + ty + i) * 1024 + n0 + tx];
  __syncthreads();
#pragma unroll
  for (int i = 0; i < 32; i += 8)
    WT[(size_t)(n0 + ty + i) * 1024 + k0 + tx] = f2bf(t[tx][ty + i]);
}

// ---------------- 128x128 tile GEMM, fused QKV; Q output pre-scaled by log2(e) ----------------
__global__ __launch_bounds__(256, 2) void gemm_qkv(
    const unsigned short* __restrict__ A, const unsigned short* __restrict__ BT,
    unsigned short* __restrict__ O0, unsigned short* __restrict__ O1,
    unsigned short* __restrict__ O2) {
  __shared__ __align__(16) unsigned short aT[128 * 64];
  __shared__ __align__(16) unsigned short bT[128 * 64];
  const int tid = threadIdx.x;
  const int lane = tid & 63, w = tid >> 6;
  const int l15 = lane & 15, l4 = lane >> 4;
  const int m0 = blockIdx.y * 128, n0 = blockIdx.x * 128;
  const int wr = w >> 1, wc = w & 1;

  const f32x4 fzero = {0.f, 0.f, 0.f, 0.f};
  f32x4 acc[4][4];
#pragma unroll
  for (int i = 0; i < 4; ++i)
#pragma unroll
    for (int j = 0; j < 4; ++j) acc[i][j] = fzero;

  for (int k0 = 0; k0 < 1024; k0 += 64) {
#pragma unroll
    for (int p = 0; p < 4; ++p) {
      int slot = (p * 4 + w) * 64 + lane;
      int row = slot >> 3, s = slot & 7;
      int ks = (s ^ (row & 7)) << 3;  // XOR swizzle on 16B slots
      GLD16(A + (size_t)(m0 + row) * 1024 + k0 + ks, (char*)aT + (p * 4 + w) * 1024);
      GLD16(BT + (size_t)(n0 + row) * 1024 + k0 + ks, (char*)bT + (p * 4 + w) * 1024);
    }
    __syncthreads();
#pragma unroll
    for (int kk = 0; kk < 2; ++kk) {
      int slotk = kk * 4 + l4;
      s16x8 af[4], bfr[4];
#pragma unroll
      for (int mi = 0; mi < 4; ++mi) {
        int row = wr * 64 + mi * 16 + l15;
        af[mi] = *(const s16x8*)(aT + row * 64 + ((slotk ^ (row & 7)) << 3));
      }
#pragma unroll
      for (int nj = 0; nj < 4; ++nj) {
        int row = wc * 64 + nj * 16 + l15;
        bfr[nj] = *(const s16x8*)(bT + row * 64 + ((slotk ^ (row & 7)) << 3));
      }
      __builtin_amdgcn_s_setprio(1);
#pragma unroll
      for (int mi = 0; mi < 4; ++mi)
#pragma unroll
        for (int nj = 0; nj < 4; ++nj)
          acc[mi][nj] = __builtin_amdgcn_mfma_f32_16x16x32_bf16(af[mi], bfr[nj], acc[mi][nj], 0, 0, 0);
      __builtin_amdgcn_s_setprio(0);
    }
    __syncthreads();
  }

#pragma unroll
  for (int mi = 0; mi < 4; ++mi)
#pragma unroll
    for (int nj = 0; nj < 4; ++nj)
#pragma unroll
      for (int r = 0; r < 4; ++r) {
        int row = m0 + wr * 64 + mi * 16 + l4 * 4 + r;  // C/D: col=lane&15, row=(lane>>4)*4+r
        int col = n0 + wc * 64 + nj * 16 + l15;
        int which = col >> 10;
        int cc = col & 1023;
        int b = row >> 11, s2 = row & 2047, hh = cc >> 6, d = cc & 63;
        if (which == 0)  // Q: pre-scale by log2(e) so attn exp2 arg is the raw accumulator
          O0[((size_t)((b * 16 + hh) * 2048 + s2)) * 64 + d] =
              f2bf(acc[mi][nj][r] * 1.4426950408889634f);
        else if (which == 1)
          O1[((size_t)((b * 16 + hh) * 2048 + s2)) * 64 + d] = f2bf(acc[mi][nj][r]);
        else
          O2[((size_t)((b * 16 + hh) * 64 + d)) * 2048 + s2] = f2bf(acc[mi][nj][r]);
      }
}

// ---------------- out-proj GEMM: 128x64 tiles, out f32 [4096][1024] ----------------
__global__ __launch_bounds__(256, 2) void gemm_op(
    const unsigned short* __restrict__ A, const unsigned short* __restrict__ BT,
    float* __restrict__ O) {
  __shared__ __align__(16) unsigned short aT[128 * 64];
  __shared__ __align__(16) unsigned short bT[64 * 64];
  const int tid = threadIdx.x;
  const int lane = tid & 63, w = tid >> 6;
  const int l15 = lane & 15, l4 = lane >> 4;
  const int m0 = blockIdx.y * 128, n0 = blockIdx.x * 64;
  const int wr = w >> 1, wc = w & 1;

  const f32x4 fzero = {0.f, 0.f, 0.f, 0.f};
  f32x4 acc[4][2];
#pragma unroll
  for (int i = 0; i < 4; ++i)
#pragma unroll
    for (int j = 0; j < 2; ++j) acc[i][j] = fzero;

  for (int k0 = 0; k0 < 1024; k0 += 64) {
#pragma unroll
    for (int p = 0; p < 4; ++p) {
      int slot = (p * 4 + w) * 64 + lane;
      int row = slot >> 3, s = slot & 7;
      int ks = (s ^ (row & 7)) << 3;
      GLD16(A + (size_t)(m0 + row) * 1024 + k0 + ks, (char*)aT + (p * 4 + w) * 1024);
    }
#pragma unroll
    for (int p = 0; p < 2; ++p) {
      int slot = (p * 4 + w) * 64 + lane;
      int row = slot >> 3, s = slot & 7;
      int ks = (s ^ (row & 7)) << 3;
      GLD16(BT + (size_t)(n0 + row) * 1024 + k0 + ks, (char*)bT + (p * 4 + w) * 1024);
    }
    __syncthreads();
#pragma unroll
    for (int kk = 0; kk < 2; ++kk) {
      int slotk = kk * 4 + l4;
      s16x8 af[4], bfr[2];
#pragma unroll
      for (int mi = 0; mi < 4; ++mi) {
        int row = wr * 64 + mi * 16 + l15;
        af[mi] = *(const s16x8*)(aT + row * 64 + ((slotk ^ (row & 7)) << 3));
      }
#pragma unroll
      for (int nj = 0; nj < 2; ++nj) {
        int row = wc * 32 + nj * 16 + l15;
        bfr[nj] = *(const s16x8*)(bT + row * 64 + ((slotk ^ (row & 7)) << 3));
      }
      __builtin_amdgcn_s_setprio(1);
#pragma unroll
      for (int mi = 0; mi < 4; ++mi)
#pragma unroll
        for (int nj = 0; nj < 2; ++nj)
          acc[mi][nj] = __builtin_amdgcn_mfma_f32_16x16x32_bf16(af[mi], bfr[nj], acc[mi][nj], 0, 0, 0);
      __builtin_amdgcn_s_setprio(0);
    }
    __syncthreads();
  }

#pragma unroll
  for (int mi = 0; mi < 4; ++mi)
#pragma unroll
    for (int nj = 0; nj < 2; ++nj)
#pragma unroll
      for (int r = 0; r < 4; ++r) {
        int row = m0 + wr * 64 + mi * 16 + l4 * 4 + r;
        int col = n0 + wc * 32 + nj * 16 + l15;
        O[(size_t)row * 1024 + col] = acc[mi][nj][r];
      }
}

// ---------------- flash attention, kv-split, swapped 32x32 MFMA, NO-MAX softmax ----------------
// grid (16, 32), 512 threads. 128 q-rows/block; wave w: q sub-tile (w&3), kv half (w>>2).
// Each kv half: 16 tiles of 64, double-buffered. Partials combined by addition in LDS.
// Bias loads go STRAIGHT into the MFMA C-in registers (no ping-pong arrays).
__global__ __launch_bounds__(512, 2) void attn_k(
    const unsigned short* __restrict__ Q,   // [32][2048][64], pre-scaled by log2(e)
    const unsigned short* __restrict__ K,   // [32][2048][64]
    const unsigned short* __restrict__ VT,  // [32][64][2048]
    const float* __restrict__ btab,         // [16][4096], pre-scaled by log2(e)
    unsigned short* __restrict__ H) {       // [2][2048][1024] bf16
  // layout: stream st (0/1): K at st*32768 + buf*8192, V at st*32768 + 16384 + buf*8192
  __shared__ __align__(16) char smem[65536];
  const int tid = threadIdx.x;
  const int lane = tid & 63, w = tid >> 6;
  const int l31 = lane & 31, l5 = lane >> 5;
  const int half = w >> 2;                 // kv stream
  const int q0 = blockIdx.x * 128 + (w & 3) * 32;
  const int bh = blockIdx.y, h = bh & 15, b = bh >> 4;
  const unsigned short* Qp = Q + (size_t)bh * 2048 * 64;
  const unsigned short* Kp = K + (size_t)bh * 2048 * 64;
  const unsigned short* Vp = VT + (size_t)bh * 64 * 2048;
  const float* btq = btab + h * 4096 + 2047 - (q0 + l31) + 4 * l5 + half * 1024;

// stage K+V for BOTH streams, tile kvv (relative to stream base), into buffer `buf`
#define STAGE(buf, kvv)                                                              \
  {                                                                                  \
    int row_ = tid >> 3, s_ = tid & 7;                                               \
    int ks_ = (s_ ^ (row_ & 7)) << 3;                                                \
    GLD16(Kp + (size_t)((kvv) + row_) * 64 + ks_, smem + (buf) * 8192 + tid * 16);   \
    GLD16(Kp + (size_t)(1024 + (kvv) + row_) * 64 + ks_,                             \
          smem + 32768 + (buf) * 8192 + tid * 16);                                   \
    GLD16(Vp + (size_t)row_ * 2048 + (kvv) + ks_,                                    \
          smem + 16384 + (buf) * 8192 + tid * 16);                                   \
    GLD16(Vp + (size_t)row_ * 2048 + 1024 + (kvv) + ks_,                             \
          smem + 16384 + 32768 + (buf) * 8192 + tid * 16);                           \
  }

  // hoist Q fragments (B operand: col=q=l31, k = ks*16 + l5*8 + j)
  s16x8 qf[4];
#pragma unroll
  for (int ks = 0; ks < 4; ++ks)
    qf[ks] = *(const s16x8*)(Qp + (size_t)(q0 + l31) * 64 + ks * 16 + l5 * 8);

  f32x16 oacc[2];
#pragma unroll
  for (int r = 0; r < 16; ++r) { oacc[0][r] = 0.f; oacc[1][r] = 0.f; }
  float s4[4] = {0.f, 0.f, 0.f, 0.f};  // lane-local running row-sum partials

  STAGE(0, 0);
  __syncthreads();
  int cur = 0;
  const char* kbase = smem + half * 32768;
  const char* vbase = smem + half * 32768 + 16384;

#define BODY(KVV)                                                                    \
  {                                                                                  \
    const int kvv = (KVV);                                                           \
    if (kvv + 64 < 1024) STAGE(cur ^ 1, kvv + 64);                                   \
    /* bias straight into C-in (C row formula m74/m101) */                           \
    f32x16 st[2];                                                                    \
    _Pragma("unroll") for (int t = 0; t < 2; ++t)                                    \
      _Pragma("unroll") for (int r = 0; r < 16; ++r)                                 \
        st[t][r] = btq[kvv + t * 32 + (r & 3) + 8 * (r >> 2)];                       \
    const char* kl = kbase + cur * 8192;                                             \
    __builtin_amdgcn_s_setprio(1);                                                   \
    _Pragma("unroll") for (int ks = 0; ks < 4; ++ks) {                               \
      int sl = ks * 2 + l5;                                                          \
      int sw = (sl ^ (l31 & 7)) << 4;                                                \
      s16x8 ka0 = *(const s16x8*)(kl + l31 * 128 + sw);                              \
      s16x8 ka1 = *(const s16x8*)(kl + (32 + l31) * 128 + sw);                       \
      st[0] = __builtin_amdgcn_mfma_f32_32x32x16_bf16(ka0, qf[ks], st[0], 0, 0, 0);  \
      st[1] = __builtin_amdgcn_mfma_f32_32x32x16_bf16(ka1, qf[ks], st[1], 0, 0, 0);  \
    }                                                                                \
    __builtin_amdgcn_s_setprio(0);                                                   \
    _Pragma("unroll") for (int t = 0; t < 2; ++t)                                    \
      _Pragma("unroll") for (int r = 0; r < 16; ++r) {                               \
        float p_ = EXP2(st[t][r]);                                                   \
        st[t][r] = p_;                                                               \
        s4[r & 3] += p_;                                                             \
      }                                                                              \
    s16x8 pb[4];                                                                     \
    _Pragma("unroll") for (int t = 0; t < 2; ++t)                                    \
      _Pragma("unroll") for (int hh = 0; hh < 2; ++hh) {                             \
        unsigned cA = cvtpk(st[t][hh * 8 + 0], st[t][hh * 8 + 1]);                   \
        unsigned cB = cvtpk(st[t][hh * 8 + 2], st[t][hh * 8 + 3]);                   \
        unsigned cC = cvtpk(st[t][hh * 8 + 4], st[t][hh * 8 + 5]);                   \
        unsigned cD = cvtpk(st[t][hh * 8 + 6], st[t][hh * 8 + 7]);                   \
        u32x2 s1 = __builtin_amdgcn_permlane32_swap(cA, cC, false, false);           \
        u32x2 s2 = __builtin_amdgcn_permlane32_swap(cB, cD, false, false);           \
        union { unsigned u[4]; s16x8 v; } pu;                                        \
        pu.u[0] = s1.x; pu.u[1] = s2.x; pu.u[2] = s1.y; pu.u[3] = s2.y;              \
        pb[t * 2 + hh] = pu.v;                                                       \
      }                                                                              \
    const char* vl = vbase + cur * 8192;                                             \
    __builtin_amdgcn_s_setprio(1);                                                   \
    _Pragma("unroll") for (int ks2 = 0; ks2 < 4; ++ks2) {                            \
      int sl = ks2 * 2 + l5;                                                         \
      int sw = (sl ^ (l31 & 7)) << 4;                                                \
      s16x8 va0 = *(const s16x8*)(vl + l31 * 128 + sw);                              \
      s16x8 va1 = *(const s16x8*)(vl + (32 + l31) * 128 + sw);                       \
      oacc[0] = __builtin_amdgcn_mfma_f32_32x32x16_bf16(va0, pb[ks2], oacc[0], 0, 0, 0); \
      oacc[1] = __builtin_amdgcn_mfma_f32_32x32x16_bf16(va1, pb[ks2], oacc[1], 0, 0, 0); \
    }                                                                                \
    __builtin_amdgcn_s_setprio(0);                                                   \
    __syncthreads();                                                                 \
    cur ^= 1;                                                                        \
  }

  for (int s = 0; s < 16; ++s) BODY(s * 64);
#undef BODY
#undef STAGE

  // per-wave row sum: lane partials + cross-half swap (both halves share q=l31)
  float sum = (s4[0] + s4[1]) + (s4[2] + s4[3]);
  u32x2 rs = __builtin_amdgcn_permlane32_swap(__float_as_uint(sum), __float_as_uint(sum), false, false);
  float lsum = __uint_as_float(rs.x) + __uint_as_float(rs.y);

  // combine kv halves: waves 4-7 publish (32 f32 O^T + sum), waves 0-3 reduce + store.
  float* comb = (float*)smem;  // 4*64*34*4B = 34816B, reuses K/V region (loop done)
  if (w >= 4) {
    float* p = comb + ((w - 4) * 64 + lane) * 34;
#pragma unroll
    for (int r = 0; r < 16; ++r) { p[r] = oacc[0][r]; p[16 + r] = oacc[1][r]; }
    p[32] = lsum;
  }
  __syncthreads();
  if (w < 4) {
    const float* p = comb + (w * 64 + lane) * 34;
#pragma unroll
    for (int r = 0; r < 16; ++r) { oacc[0][r] += p[r]; oacc[1][r] += p[16 + r]; }
    float inv = 1.0f / (lsum + p[32]);
    size_t hb = (((size_t)(b * 2048 + q0 + l31)) * 1024 + h * 64 + 4 * l5) * 2;
#pragma unroll
    for (int nd = 0; nd < 2; ++nd)
#pragma unroll
      for (int g = 0; g < 4; ++g) {
        unsigned w0 = cvtpk(oacc[nd][g * 4 + 0] * inv, oacc[nd][g * 4 + 1] * inv);
        unsigned w1 = cvtpk(oacc[nd][g * 4 + 2] * inv, oacc[nd][g * 4 + 3] * inv);
        unsigned long long pk8 = (unsigned long long)w0 | ((unsigned long long)w1 << 32);
        *(unsigned long long*)((char*)H + hb + (nd * 32 + 8 * g) * 2) = pk8;
      }
  }
}

extern "C" void kernel_launch(void* const* d_in, const int* in_sizes, int n_in,
                              void* d_out, int out_size, void* d_ws, size_t ws_size,
                              hipStream_t stream) {
  const float* X   = (const float*)d_in[0];
  const float* Wq  = (const float*)d_in[1];
  const float* Wk  = (const float*)d_in[2];
  const float* Wv  = (const float*)d_in[3];
  const float* Wo  = (const float*)d_in[4];
  const float* rel = (const float*)d_in[5];

  char* ws = (char*)d_ws;
  unsigned short* Xb     = (unsigned short*)(ws);                // 8 MiB [4096][1024]
  unsigned short* Hid    = Xb;                                   // aliased after QKV gemm
  unsigned short* WqkvT  = (unsigned short*)(ws + (8u << 20));   // 6 MiB [3072][1024]
  unsigned short* WoT    = (unsigned short*)(ws + (14u << 20));  // 2 MiB
  unsigned short* Qb     = (unsigned short*)(ws + (16u << 20));  // 8 MiB [b][h][s][d]
  unsigned short* Kb     = (unsigned short*)(ws + (24u << 20));  // 8 MiB
  unsigned short* VTb    = (unsigned short*)(ws + (32u << 20));  // 8 MiB [b][h][d][s]
  float* btab            = (float*)(ws + (40u << 20));           // 256 KiB [16][4096]

  cvt_lin<<<1024, 256, 0, stream>>>(X, Xb, (2 * 2048 * 1024) / 4);
  cvt_prep<<<dim3(32, 32, 5), 256, 0, stream>>>(Wq, Wk, Wv, Wo, rel, WqkvT, WoT, btab);

  gemm_qkv<<<dim3(24, 32), 256, 0, stream>>>(Xb, WqkvT, Qb, Kb, VTb);

  attn_k<<<dim3(16, 32), 512, 0, stream>>>(Qb, Kb, VTb, btab, Hid);

  gemm_op<<<dim3(16, 32), 256, 0, stream>>>(Hid, WoT, (float*)d_out);
}